// Round 4
// baseline (199.358 us; speedup 1.0000x reference)
//
#include <hip/hip_runtime.h>
#include <math.h>

#define HX 48
#define WX 48
#define OMC 216
#define HY 96
#define WY 96

// ws layout (floats):
//  om  : 4*216*2304   = 1,990,656
//  wt2 : 9*64*256     =   147,456
//  wt1 : 9*64*64      =    36,864
//  yt  : 4*9216*64    = 2,359,296
//  rs  : 4*9*8*3*9216 = 7,962,624   (py, px, m per (b,k,g,px96))

// ---------- prep: wt2[k][ic][oc256] from w_om; wt1[k][c][oc64] from w_dc ----------
__global__ __launch_bounds__(256) void prep_w_kernel(
    const float* __restrict__ w_om, const float* __restrict__ w_dc,
    float* __restrict__ wt2, float* __restrict__ wt1) {
  int idx = blockIdx.x * 256 + threadIdx.x;
  if (idx < 9 * 64 * 256) {
    int oc = idx & 255, ic = (idx >> 8) & 63, k = idx >> 14;
    wt2[idx] = (oc < OMC) ? w_om[oc * 576 + ic * 9 + k] : 0.0f;
  } else {
    int j = idx - 9 * 64 * 256;  // < 36864
    int oc = j & 63, c = (j >> 6) & 63, k = j >> 12;
    wt1[j] = w_dc[oc * 576 + c * 9 + k];
  }
}

// ---------- y[b][c][p] -> yt[b][p][c] ----------
__global__ __launch_bounds__(256) void ytr_kernel(const float* __restrict__ y,
                                                  float* __restrict__ yt) {
  __shared__ float tile[64][65];
  int blk = blockIdx.x;  // 576 = 4b * 144
  int b = blk / 144;
  int p0 = (blk % 144) * 64;
  int t = threadIdx.x;
  int pl = t & 63;
  int cb = t >> 6;
#pragma unroll
  for (int i = 0; i < 16; ++i) {
    int c = cb * 16 + i;
    tile[c][pl] = y[((size_t)(b * 64 + c)) * 9216 + p0 + pl];
  }
  __syncthreads();
  int cw = t & 63;
  int pb = t >> 6;
#pragma unroll
  for (int i = 0; i < 16; ++i) {
    int p = pb * 16 + i;
    yt[((size_t)(b * 9216 + p0 + p)) * 64 + cw] = tile[cw][p];
  }
}

// ---------- conv as pipelined GEMM: 256oc x 16px per block, K=576 ----------
__global__ __launch_bounds__(256) void conv_gemm_kernel(
    const float* __restrict__ x, const float* __restrict__ wt2,
    const float* __restrict__ bom, float* __restrict__ om) {
  __shared__ float sv[2][64 * 16];
  int t = threadIdx.x;
  int bid = blockIdx.x;
  int logical = (bid & 7) * 72 + (bid >> 3);   // XCD swizzle (576 % 8 == 0)
  int b = logical / 144;
  int tile = logical % 144;
  int h0 = (tile / 12) * 4;
  int w0 = (tile % 12) * 4;
  int ocq = t & 63;
  int pxq = t >> 6;
  int s_ic = t >> 2;
  int s_row = t & 3;
  const float* xp = x + (size_t)b * 64 * 2304 + (size_t)s_ic * 2304;

  float acc[4][4];
#pragma unroll
  for (int i = 0; i < 4; ++i)
#pragma unroll
    for (int j = 0; j < 4; ++j) acc[i][j] = 0.0f;

  auto loadx = [&](int k, float4& v) {
    int dy = k / 3 - 1, dx = k % 3 - 1;
    int hh = h0 + s_row + dy;
    int ww = w0 + dx;
    bool hv = (unsigned)hh < (unsigned)HX;
    int hc = min(max(hh, 0), HX - 1);
    const float* xr = xp + hc * WX;
    int wc0 = min(max(ww + 0, 0), WX - 1);
    int wc1 = min(max(ww + 1, 0), WX - 1);
    int wc2 = min(max(ww + 2, 0), WX - 1);
    int wc3 = min(max(ww + 3, 0), WX - 1);
    v.x = xr[wc0] * ((hv && (unsigned)(ww + 0) < (unsigned)WX) ? 1.f : 0.f);
    v.y = xr[wc1] * ((hv && (unsigned)(ww + 1) < (unsigned)WX) ? 1.f : 0.f);
    v.z = xr[wc2] * ((hv && (unsigned)(ww + 2) < (unsigned)WX) ? 1.f : 0.f);
    v.w = xr[wc3] * ((hv && (unsigned)(ww + 3) < (unsigned)WX) ? 1.f : 0.f);
  };

#define CONV_GEMM(K, BUF)                                          \
  {                                                                \
    const float* wk = wt2 + (K) * 16384;                           \
    const float* svc = &sv[BUF][0];                                \
    _Pragma("unroll 8") for (int c = 0; c < 64; ++c) {             \
      float4 wv = *(const float4*)&wk[c * 256 + 4 * ocq];          \
      float4 vv = *(const float4*)&svc[c * 16 + 4 * pxq];          \
      acc[0][0] += wv.x * vv.x; acc[0][1] += wv.x * vv.y;          \
      acc[0][2] += wv.x * vv.z; acc[0][3] += wv.x * vv.w;          \
      acc[1][0] += wv.y * vv.x; acc[1][1] += wv.y * vv.y;          \
      acc[1][2] += wv.y * vv.z; acc[1][3] += wv.y * vv.w;          \
      acc[2][0] += wv.z * vv.x; acc[2][1] += wv.z * vv.y;          \
      acc[2][2] += wv.z * vv.z; acc[2][3] += wv.z * vv.w;          \
      acc[3][0] += wv.w * vv.x; acc[3][1] += wv.w * vv.y;          \
      acc[3][2] += wv.w * vv.z; acc[3][3] += wv.w * vv.w;          \
    }                                                              \
  }

  {
    float4 v;
    loadx(0, v);
    *(float4*)&sv[0][s_ic * 16 + s_row * 4] = v;
  }
  __syncthreads();
  for (int k = 0; k < 8; ++k) {
    int cur = k & 1;
    float4 vn;
    loadx(k + 1, vn);                       // issue early, hides under GEMM
    CONV_GEMM(k, cur);
    *(float4*)&sv[cur ^ 1][s_ic * 16 + s_row * 4] = vn;
    __syncthreads();
  }
  CONV_GEMM(8, 0);

#pragma unroll
  for (int i = 0; i < 4; ++i) {
    int oc = 4 * ocq + i;
    if (oc < OMC) {
      float bv = bom[oc];
      float4 o;
      o.x = acc[i][0] + bv; o.y = acc[i][1] + bv;
      o.z = acc[i][2] + bv; o.w = acc[i][3] + bv;
      *(float4*)&om[((size_t)(b * OMC + oc)) * 2304 + (h0 + pxq) * WX + w0] = o;
    }
  }
#undef CONV_GEMM
}

// ---------- resize: om(48x48) -> absolute sample coords + sigmoid mask @96x96 ----
__global__ __launch_bounds__(256) void resize_kernel(const float* __restrict__ om,
                                                     float* __restrict__ rs) {
  int idx = blockIdx.x * 256 + threadIdx.x;  // 4*9*8*9216 = 2,654,208
  int px = idx % 9216;
  int r = idx / 9216;   // b*72 + k*8 + g
  int g = r % 8;
  int k = (r / 8) % 9;
  int b = r / 72;
  int h = px / 96, w = px % 96;
  float sh = fmaxf(h * 0.5f - 0.25f, 0.f);
  float sw = fmaxf(w * 0.5f - 0.25f, 0.f);
  int i0h = (int)sh; float th = sh - (float)i0h;
  int i0w = (int)sw; float tw = sw - (float)i0w;
  int i1h = min(i0h + 1, HX - 1);
  int i1w = min(i0w + 1, WX - 1);
  float r00 = (1.f - th) * (1.f - tw), r01 = (1.f - th) * tw;
  float r10 = th * (1.f - tw),         r11 = th * tw;
  int a00 = i0h * WX + i0w, a01 = i0h * WX + i1w;
  int a10 = i1h * WX + i0w, a11 = i1h * WX + i1w;
  const float* omb = om + (size_t)b * OMC * 2304;
  const float* cy = omb + (size_t)(g * 18 + k * 2) * 2304;
  const float* cx = cy + 2304;
  const float* cm = omb + (size_t)(144 + g * 9 + k) * 2304;
  float oy = r00 * cy[a00] + r01 * cy[a01] + r10 * cy[a10] + r11 * cy[a11];
  float ox = r00 * cx[a00] + r01 * cx[a01] + r10 * cx[a10] + r11 * cx[a11];
  float mv = r00 * cm[a00] + r01 * cm[a01] + r10 * cm[a10] + r11 * cm[a11];
  float mm = 1.f / (1.f + __expf(-mv));
  int dy = k / 3 - 1, dx = k % 3 - 1;
  float* o = rs + (size_t)(((b * 9 + k) * 8 + g) * 3) * 9216 + px;
  o[0]     = (float)(h + dy) + oy;
  o[9216]  = (float)(w + dx) + ox;
  o[18432] = mm;
}

// ---------- deform: pipelined gather + GEMM (64oc x 64px, K=576) ----------
// NOTE: 3rd macro param must NOT be named w/x/y/z/s/d — member-access capture!
#define MAD4(d, s, mw)                                                  \
  d.x += (mw) * s.x; d.y += (mw) * s.y; d.z += (mw) * s.z; d.w += (mw) * s.w;

__global__ __launch_bounds__(256) void deform_gemm_kernel(
    const float* __restrict__ yt, const float* __restrict__ rs,
    const float* __restrict__ wt1, const float* __restrict__ bdc,
    float* __restrict__ out) {
  __shared__ float sv[2][64 * 68];
  int t = threadIdx.x;
  int bid = blockIdx.x;
  int logical = (bid & 7) * 72 + (bid >> 3);   // XCD swizzle
  int b = logical / 144;
  int tile = logical % 144;
  int h0 = (tile / 12) * 8;
  int w0 = (tile % 12) * 8;
  int ocq = t & 15;
  int pxq = t >> 4;
  int gpx = t & 63;
  int gb = t >> 6;               // this thread gathers groups gb and gb+4
  int gh = h0 + (gpx >> 3);
  int gw = w0 + (gpx & 7);
  int px96 = gh * WY + gw;
  const float* rsb = rs + (size_t)b * 1990656 + px96;   // 9*8*3*9216
  const float* ytb = yt + (size_t)b * 9216 * 64;

  float acc[4][4];
#pragma unroll
  for (int i = 0; i < 4; ++i)
#pragma unroll
    for (int j = 0; j < 4; ++j) acc[i][j] = 0.0f;

#define DGEMM_HALF(K, BUF, C0)                                     \
  {                                                                \
    const float* wk = wt1 + (K) * 4096;                            \
    const float* svc = &sv[BUF][0];                                \
    _Pragma("unroll") for (int cc = 0; cc < 32; ++cc) {            \
      int c = (C0) + cc;                                           \
      float4 wv = *(const float4*)&wk[c * 64 + 4 * ocq];           \
      float4 vv = *(const float4*)&svc[c * 68 + 4 * pxq];          \
      acc[0][0] += wv.x * vv.x; acc[0][1] += wv.x * vv.y;          \
      acc[0][2] += wv.x * vv.z; acc[0][3] += wv.x * vv.w;          \
      acc[1][0] += wv.y * vv.x; acc[1][1] += wv.y * vv.y;          \
      acc[1][2] += wv.y * vv.z; acc[1][3] += wv.y * vv.w;          \
      acc[2][0] += wv.z * vv.x; acc[2][1] += wv.z * vv.y;          \
      acc[2][2] += wv.z * vv.z; acc[2][3] += wv.z * vv.w;          \
      acc[3][0] += wv.w * vv.x; acc[3][1] += wv.w * vv.y;          \
      acc[3][2] += wv.w * vv.z; acc[3][3] += wv.w * vv.w;          \
    }                                                              \
  }

  // full (non-pipelined) gather for k=0 into buf 0
  {
#pragma unroll
    for (int gg = 0; gg < 2; ++gg) {
      int g = gb + gg * 4;
      const float* r0 = rsb + (size_t)((0 * 8 + g) * 3) * 9216;
      float py = r0[0], pxf = r0[9216], m = r0[18432];
      float y0f = floorf(py), x0f = floorf(pxf);
      float ty = py - y0f, tx = pxf - x0f;
      int y0 = (int)y0f, x0 = (int)x0f;
      int y1 = y0 + 1, x1 = x0 + 1;
      float w00 = (1.f - ty) * (1.f - tx) * m, w01 = (1.f - ty) * tx * m;
      float w10 = ty * (1.f - tx) * m,         w11 = ty * tx * m;
      w00 = ((unsigned)y0 < HY && (unsigned)x0 < WY) ? w00 : 0.f;
      w01 = ((unsigned)y0 < HY && (unsigned)x1 < WY) ? w01 : 0.f;
      w10 = ((unsigned)y1 < HY && (unsigned)x0 < WY) ? w10 : 0.f;
      w11 = ((unsigned)y1 < HY && (unsigned)x1 < WY) ? w11 : 0.f;
      int y0c = min(max(y0, 0), HY - 1), y1c = min(max(y1, 0), HY - 1);
      int x0c = min(max(x0, 0), WY - 1), x1c = min(max(x1, 0), WY - 1);
      int gc = g * 8;
      const float* p00 = ytb + (size_t)(y0c * WY + x0c) * 64 + gc;
      const float* p01 = ytb + (size_t)(y0c * WY + x1c) * 64 + gc;
      const float* p10 = ytb + (size_t)(y1c * WY + x0c) * 64 + gc;
      const float* p11 = ytb + (size_t)(y1c * WY + x1c) * 64 + gc;
      float4 s0 = {0, 0, 0, 0}, s1 = {0, 0, 0, 0};
      float4 cA, cB;
      cA = *(const float4*)p00; cB = *(const float4*)(p00 + 4);
      MAD4(s0, cA, w00) MAD4(s1, cB, w00)
      cA = *(const float4*)p01; cB = *(const float4*)(p01 + 4);
      MAD4(s0, cA, w01) MAD4(s1, cB, w01)
      cA = *(const float4*)p10; cB = *(const float4*)(p10 + 4);
      MAD4(s0, cA, w10) MAD4(s1, cB, w10)
      cA = *(const float4*)p11; cB = *(const float4*)(p11 + 4);
      MAD4(s0, cA, w11) MAD4(s1, cB, w11)
      sv[0][(gc + 0) * 68 + gpx] = s0.x;
      sv[0][(gc + 1) * 68 + gpx] = s0.y;
      sv[0][(gc + 2) * 68 + gpx] = s0.z;
      sv[0][(gc + 3) * 68 + gpx] = s0.w;
      sv[0][(gc + 4) * 68 + gpx] = s1.x;
      sv[0][(gc + 5) * 68 + gpx] = s1.y;
      sv[0][(gc + 6) * 68 + gpx] = s1.z;
      sv[0][(gc + 7) * 68 + gpx] = s1.w;
    }
  }
  __syncthreads();

  for (int k = 0; k < 8; ++k) {
    int cur = k & 1;
    // Phase A: rs prefetch for k+1 (independent loads, issue before GEMM)
    float py[2], pxf[2], mq[2];
#pragma unroll
    for (int gg = 0; gg < 2; ++gg) {
      const float* r0 = rsb + (size_t)((((k + 1) * 8) + gb + gg * 4) * 3) * 9216;
      py[gg] = r0[0]; pxf[gg] = r0[9216]; mq[gg] = r0[18432];
    }
    DGEMM_HALF(k, cur, 0);
    // Phase B: compute addresses, issue 16 gather loads
    float4 L[2][4][2];
    float wts[2][4];
#pragma unroll
    for (int gg = 0; gg < 2; ++gg) {
      float y0f = floorf(py[gg]), x0f = floorf(pxf[gg]);
      float ty = py[gg] - y0f, tx = pxf[gg] - x0f;
      int y0 = (int)y0f, x0 = (int)x0f;
      int y1 = y0 + 1, x1 = x0 + 1;
      float m = mq[gg];
      float w00 = (1.f - ty) * (1.f - tx) * m, w01 = (1.f - ty) * tx * m;
      float w10 = ty * (1.f - tx) * m,         w11 = ty * tx * m;
      wts[gg][0] = ((unsigned)y0 < HY && (unsigned)x0 < WY) ? w00 : 0.f;
      wts[gg][1] = ((unsigned)y0 < HY && (unsigned)x1 < WY) ? w01 : 0.f;
      wts[gg][2] = ((unsigned)y1 < HY && (unsigned)x0 < WY) ? w10 : 0.f;
      wts[gg][3] = ((unsigned)y1 < HY && (unsigned)x1 < WY) ? w11 : 0.f;
      int y0c = min(max(y0, 0), HY - 1), y1c = min(max(y1, 0), HY - 1);
      int x0c = min(max(x0, 0), WY - 1), x1c = min(max(x1, 0), WY - 1);
      int gc = (gb + gg * 4) * 8;
      const float* p00 = ytb + (size_t)(y0c * WY + x0c) * 64 + gc;
      const float* p01 = ytb + (size_t)(y0c * WY + x1c) * 64 + gc;
      const float* p10 = ytb + (size_t)(y1c * WY + x0c) * 64 + gc;
      const float* p11 = ytb + (size_t)(y1c * WY + x1c) * 64 + gc;
      L[gg][0][0] = *(const float4*)p00; L[gg][0][1] = *(const float4*)(p00 + 4);
      L[gg][1][0] = *(const float4*)p01; L[gg][1][1] = *(const float4*)(p01 + 4);
      L[gg][2][0] = *(const float4*)p10; L[gg][2][1] = *(const float4*)(p10 + 4);
      L[gg][3][0] = *(const float4*)p11; L[gg][3][1] = *(const float4*)(p11 + 4);
    }
    DGEMM_HALF(k, cur, 32);
    // Phase C: combine + write next buffer
#pragma unroll
    for (int gg = 0; gg < 2; ++gg) {
      float4 s0 = {0, 0, 0, 0}, s1 = {0, 0, 0, 0};
      MAD4(s0, L[gg][0][0], wts[gg][0]) MAD4(s1, L[gg][0][1], wts[gg][0])
      MAD4(s0, L[gg][1][0], wts[gg][1]) MAD4(s1, L[gg][1][1], wts[gg][1])
      MAD4(s0, L[gg][2][0], wts[gg][2]) MAD4(s1, L[gg][2][1], wts[gg][2])
      MAD4(s0, L[gg][3][0], wts[gg][3]) MAD4(s1, L[gg][3][1], wts[gg][3])
      int gc = (gb + gg * 4) * 8;
      float* d = &sv[cur ^ 1][gc * 68 + gpx];
      d[0 * 68] = s0.x; d[1 * 68] = s0.y; d[2 * 68] = s0.z; d[3 * 68] = s0.w;
      d[4 * 68] = s1.x; d[5 * 68] = s1.y; d[6 * 68] = s1.z; d[7 * 68] = s1.w;
    }
    __syncthreads();
  }
  DGEMM_HALF(8, 0, 0);
  DGEMM_HALF(8, 0, 32);

  // epilogue: bias + relu + store
  int py_ = pxq >> 1;
  int colb = (pxq & 1) * 4;
#pragma unroll
  for (int i = 0; i < 4; ++i) {
    int oc = 4 * ocq + i;
    float bv = bdc[oc];
    float4 o;
    o.x = fmaxf(acc[i][0] + bv, 0.0f);
    o.y = fmaxf(acc[i][1] + bv, 0.0f);
    o.z = fmaxf(acc[i][2] + bv, 0.0f);
    o.w = fmaxf(acc[i][3] + bv, 0.0f);
    *(float4*)&out[((size_t)(b * 64 + oc) * 96 + (h0 + py_)) * 96 + w0 + colb] = o;
  }
#undef DGEMM_HALF
}

extern "C" void kernel_launch(void* const* d_in, const int* in_sizes, int n_in,
                              void* d_out, int out_size, void* d_ws, size_t ws_size,
                              hipStream_t stream) {
  const float* x = (const float*)d_in[0];
  const float* y = (const float*)d_in[1];
  const float* w_om = (const float*)d_in[2];
  const float* b_om = (const float*)d_in[3];
  const float* w_dc = (const float*)d_in[4];
  const float* b_dc = (const float*)d_in[5];
  float* out = (float*)d_out;

  float* om  = (float*)d_ws;           // 1,990,656 f
  float* wt2 = om + 1990656;           //   147,456 f
  float* wt1 = wt2 + 147456;           //    36,864 f
  float* yt  = wt1 + 36864;            // 2,359,296 f
  float* rs  = yt + 2359296;           // 7,962,624 f

  prep_w_kernel<<<720, 256, 0, stream>>>(w_om, w_dc, wt2, wt1);
  ytr_kernel<<<576, 256, 0, stream>>>(y, yt);
  conv_gemm_kernel<<<576, 256, 0, stream>>>(x, wt2, b_om, om);
  resize_kernel<<<10368, 256, 0, stream>>>(om, rs);
  deform_gemm_kernel<<<576, 256, 0, stream>>>(yt, rs, wt1, b_dc, out);
}

// Round 5
// 180.685 us; speedup vs baseline: 1.1033x; 1.1033x over previous
//
#include <hip/hip_runtime.h>
#include <math.h>

#define HX 48
#define WX 48
#define OMC 216
#define HY 96
#define WY 96

// ws layout (floats):
//  om  @ 0          : 1,990,656
//  wt2 @ 1,990,656  :   147,456
//  wt1 @ 2,138,112  :    36,864
//  yt  @ 2,174,976  : 2,359,296
//  shr @ 4,534,272  : 7,962,624   (pc [3*576*4096] first, then rs reuses it)
//  pt  @ 12,496,896 : 7,077,888
//  total 19,574,784 f = ~74.7 MiB

// ---------- prep: wt2[k][ic][oc256]; wt1[k][c][oc64] ----------
__global__ __launch_bounds__(256) void prep_w_kernel(
    const float* __restrict__ w_om, const float* __restrict__ w_dc,
    float* __restrict__ wt2, float* __restrict__ wt1) {
  int idx = blockIdx.x * 256 + threadIdx.x;
  if (idx < 9 * 64 * 256) {
    int oc = idx & 255, ic = (idx >> 8) & 63, k = idx >> 14;
    wt2[idx] = (oc < OMC) ? w_om[oc * 576 + ic * 9 + k] : 0.0f;
  } else {
    int j = idx - 9 * 64 * 256;  // < 36864
    int oc = j & 63, c = (j >> 6) & 63, k = j >> 12;
    wt1[j] = w_dc[oc * 576 + c * 9 + k];
  }
}

// ---------- y[b][c][p] -> yt[b][p][c] ----------
__global__ __launch_bounds__(256) void ytr_kernel(const float* __restrict__ y,
                                                  float* __restrict__ yt) {
  __shared__ float tile[64][65];
  int blk = blockIdx.x;  // 576 = 4b * 144
  int b = blk / 144;
  int p0 = (blk % 144) * 64;
  int t = threadIdx.x;
  int pl = t & 63;
  int cb = t >> 6;
#pragma unroll
  for (int i = 0; i < 16; ++i) {
    int c = cb * 16 + i;
    tile[c][pl] = y[((size_t)(b * 64 + c)) * 9216 + p0 + pl];
  }
  __syncthreads();
  int cw = t & 63;
  int pb = t >> 6;
#pragma unroll
  for (int i = 0; i < 16; ++i) {
    int p = pb * 16 + i;
    yt[((size_t)(b * 9216 + p0 + p)) * 64 + cw] = tile[cw][p];
  }
}

// ---------- conv K-part: taps 3p..3p+2, 256oc x 16px, partials to pc ----------
__global__ __launch_bounds__(256) void conv_part_kernel(
    const float* __restrict__ x, const float* __restrict__ wt2,
    float* __restrict__ pc) {
  __shared__ float sv[2][1024];
  int t = threadIdx.x;
  int bid = blockIdx.x;                       // 1728
  int logical = (bid & 7) * 216 + (bid >> 3); // bijective XCD swizzle
  int p = logical / 576;
  int tile576 = logical % 576;
  int b = tile576 / 144;
  int tl = tile576 % 144;
  int h0 = (tl / 12) * 4;
  int w0 = (tl % 12) * 4;
  int ocq = t & 63;
  int pxq = t >> 6;
  int s_ic = t >> 2;
  int s_row = t & 3;
  int k0 = p * 3;
  const float* xp = x + (size_t)b * 64 * 2304 + (size_t)s_ic * 2304;

  float acc[4][4];
#pragma unroll
  for (int i = 0; i < 4; ++i)
#pragma unroll
    for (int j = 0; j < 4; ++j) acc[i][j] = 0.0f;

  auto loadx = [&](int k, float4& v) {
    int dy = k / 3 - 1, dx = k % 3 - 1;
    int hh = h0 + s_row + dy;
    int ww = w0 + dx;
    bool hv = (unsigned)hh < (unsigned)HX;
    int hc = min(max(hh, 0), HX - 1);
    const float* xr = xp + hc * WX;
    int wc0 = min(max(ww + 0, 0), WX - 1);
    int wc1 = min(max(ww + 1, 0), WX - 1);
    int wc2 = min(max(ww + 2, 0), WX - 1);
    int wc3 = min(max(ww + 3, 0), WX - 1);
    v.x = xr[wc0] * ((hv && (unsigned)(ww + 0) < (unsigned)WX) ? 1.f : 0.f);
    v.y = xr[wc1] * ((hv && (unsigned)(ww + 1) < (unsigned)WX) ? 1.f : 0.f);
    v.z = xr[wc2] * ((hv && (unsigned)(ww + 2) < (unsigned)WX) ? 1.f : 0.f);
    v.w = xr[wc3] * ((hv && (unsigned)(ww + 3) < (unsigned)WX) ? 1.f : 0.f);
  };

#define CONV_GEMM(K, BUF)                                          \
  {                                                                \
    const float* wk = wt2 + (K) * 16384;                           \
    const float* svc = &sv[BUF][0];                                \
    _Pragma("unroll 8") for (int c = 0; c < 64; ++c) {             \
      float4 wv = *(const float4*)&wk[c * 256 + 4 * ocq];          \
      float4 vv = *(const float4*)&svc[c * 16 + 4 * pxq];          \
      acc[0][0] += wv.x * vv.x; acc[0][1] += wv.x * vv.y;          \
      acc[0][2] += wv.x * vv.z; acc[0][3] += wv.x * vv.w;          \
      acc[1][0] += wv.y * vv.x; acc[1][1] += wv.y * vv.y;          \
      acc[1][2] += wv.y * vv.z; acc[1][3] += wv.y * vv.w;          \
      acc[2][0] += wv.z * vv.x; acc[2][1] += wv.z * vv.y;          \
      acc[2][2] += wv.z * vv.z; acc[2][3] += wv.z * vv.w;          \
      acc[3][0] += wv.w * vv.x; acc[3][1] += wv.w * vv.y;          \
      acc[3][2] += wv.w * vv.z; acc[3][3] += wv.w * vv.w;          \
    }                                                              \
  }

  {
    float4 v;
    loadx(k0, v);
    *(float4*)&sv[0][s_ic * 16 + s_row * 4] = v;
  }
  __syncthreads();
#pragma unroll
  for (int i = 0; i < 2; ++i) {
    float4 vn;
    loadx(k0 + i + 1, vn);
    CONV_GEMM(k0 + i, i & 1);
    *(float4*)&sv[(i & 1) ^ 1][s_ic * 16 + s_row * 4] = vn;
    __syncthreads();
  }
  CONV_GEMM(k0 + 2, 0);

  // store partials: pc[(p*576+tile)*4096 + oc*16 + px]
  float* pb = pc + (size_t)(p * 576 + tile576) * 4096;
#pragma unroll
  for (int i = 0; i < 4; ++i) {
    *(float4*)&pb[(4 * ocq + i) * 16 + 4 * pxq] =
        make_float4(acc[i][0], acc[i][1], acc[i][2], acc[i][3]);
  }
#undef CONV_GEMM
}

// ---------- creduce: sum 3 conv parts + bias -> om ----------
__global__ __launch_bounds__(256) void creduce_kernel(
    const float* __restrict__ pc, const float* __restrict__ bom,
    float* __restrict__ om) {
  int tile = blockIdx.x;  // 0..575
  int b = tile / 144;
  int tl = tile % 144;
  int h0 = (tl / 12) * 4;
  int w0 = (tl % 12) * 4;
  int n = threadIdx.x;            // oc = n
  if (n >= OMC) return;
  const float4* p0 = (const float4*)(pc + (size_t)(0 * 576 + tile) * 4096);
  const float4* p1 = (const float4*)(pc + (size_t)(1 * 576 + tile) * 4096);
  const float4* p2 = (const float4*)(pc + (size_t)(2 * 576 + tile) * 4096);
  float bv = bom[n];
#pragma unroll
  for (int q = 0; q < 4; ++q) {   // q = px row
    int j = n * 4 + q;
    float4 a = p0[j], c = p1[j], d = p2[j];
    float4 o;
    o.x = a.x + c.x + d.x + bv;
    o.y = a.y + c.y + d.y + bv;
    o.z = a.z + c.z + d.z + bv;
    o.w = a.w + c.w + d.w + bv;
    *(float4*)&om[((size_t)(b * OMC + n)) * 2304 + (h0 + q) * WX + w0] = o;
  }
}

// ---------- resize: om(48x48) -> abs sample coords + sigmoid mask @96x96 ----
__global__ __launch_bounds__(256) void resize_kernel(const float* __restrict__ om,
                                                     float* __restrict__ rs) {
  int idx = blockIdx.x * 256 + threadIdx.x;  // 2,654,208
  int px = idx % 9216;
  int r = idx / 9216;   // b*72 + k*8 + g
  int g = r % 8;
  int k = (r / 8) % 9;
  int b = r / 72;
  int h = px / 96, w = px % 96;
  float sh = fmaxf(h * 0.5f - 0.25f, 0.f);
  float sw = fmaxf(w * 0.5f - 0.25f, 0.f);
  int i0h = (int)sh; float th = sh - (float)i0h;
  int i0w = (int)sw; float tw = sw - (float)i0w;
  int i1h = min(i0h + 1, HX - 1);
  int i1w = min(i0w + 1, WX - 1);
  float r00 = (1.f - th) * (1.f - tw), r01 = (1.f - th) * tw;
  float r10 = th * (1.f - tw),         r11 = th * tw;
  int a00 = i0h * WX + i0w, a01 = i0h * WX + i1w;
  int a10 = i1h * WX + i0w, a11 = i1h * WX + i1w;
  const float* omb = om + (size_t)b * OMC * 2304;
  const float* cy = omb + (size_t)(g * 18 + k * 2) * 2304;
  const float* cx = cy + 2304;
  const float* cm = omb + (size_t)(144 + g * 9 + k) * 2304;
  float oy = r00 * cy[a00] + r01 * cy[a01] + r10 * cy[a10] + r11 * cy[a11];
  float ox = r00 * cx[a00] + r01 * cx[a01] + r10 * cx[a10] + r11 * cx[a11];
  float mv = r00 * cm[a00] + r01 * cm[a01] + r10 * cm[a10] + r11 * cm[a11];
  float mm = 1.f / (1.f + __expf(-mv));
  int dy = k / 3 - 1, dx = k % 3 - 1;
  float* o = rs + (size_t)(((b * 9 + k) * 8 + g) * 3) * 9216 + px;
  o[0]     = (float)(h + dy) + oy;
  o[9216]  = (float)(w + dx) + ox;
  o[18432] = mm;
}

// ---------- deform K-part: taps 3p..3p+2, 64oc x 64px, partials to pt ----------
// NOTE: 3rd macro param must NOT be named w/x/y/z/s/d — member-access capture!
#define MAD4(d, s, mw)                                                  \
  d.x += (mw) * s.x; d.y += (mw) * s.y; d.z += (mw) * s.z; d.w += (mw) * s.w;

__global__ __launch_bounds__(256) void deform_part_kernel(
    const float* __restrict__ yt, const float* __restrict__ rs,
    const float* __restrict__ wt1, float* __restrict__ pt) {
  __shared__ float sv[2][64 * 64];              // 32768 B -> 5 blocks/CU
  int t = threadIdx.x;
  int bid = blockIdx.x;                         // 1728
  int logical = (bid & 7) * 216 + (bid >> 3);   // bijective XCD swizzle
  int p = logical / 576;
  int tile576 = logical % 576;
  int b = tile576 / 144;
  int tl = tile576 % 144;
  int h0 = (tl / 12) * 8;
  int w0 = (tl % 12) * 8;
  int k0 = p * 3;
  int ocq = t & 15;
  int pxq = t >> 4;
  int gpx = t & 63;
  int gb = t >> 6;               // gathers groups gb and gb+4
  int gh = h0 + (gpx >> 3);
  int gw = w0 + (gpx & 7);
  int px96 = gh * WY + gw;
  const float* rsb = rs + (size_t)b * 1990656 + px96;   // 9*8*3*9216
  const float* ytb = yt + (size_t)b * 9216 * 64;

  float acc[4][4];
#pragma unroll
  for (int i = 0; i < 4; ++i)
#pragma unroll
    for (int j = 0; j < 4; ++j) acc[i][j] = 0.0f;

#define DGEMM_HALF(K, BUF, C0)                                     \
  {                                                                \
    const float* wk = wt1 + (K) * 4096;                            \
    const float* svc = &sv[BUF][0];                                \
    _Pragma("unroll") for (int cc = 0; cc < 32; ++cc) {            \
      int c = (C0) + cc;                                           \
      float4 wv = *(const float4*)&wk[c * 64 + 4 * ocq];           \
      float4 vv = *(const float4*)&svc[c * 64 + 4 * pxq];          \
      acc[0][0] += wv.x * vv.x; acc[0][1] += wv.x * vv.y;          \
      acc[0][2] += wv.x * vv.z; acc[0][3] += wv.x * vv.w;          \
      acc[1][0] += wv.y * vv.x; acc[1][1] += wv.y * vv.y;          \
      acc[1][2] += wv.y * vv.z; acc[1][3] += wv.y * vv.w;          \
      acc[2][0] += wv.z * vv.x; acc[2][1] += wv.z * vv.y;          \
      acc[2][2] += wv.z * vv.z; acc[2][3] += wv.z * vv.w;          \
      acc[3][0] += wv.w * vv.x; acc[3][1] += wv.w * vv.y;          \
      acc[3][2] += wv.w * vv.z; acc[3][3] += wv.w * vv.w;          \
    }                                                              \
  }

  // prologue gather: tap k0 into sv[0]
  {
#pragma unroll
    for (int gg = 0; gg < 2; ++gg) {
      int g = gb + gg * 4;
      const float* r0 = rsb + (size_t)((k0 * 8 + g) * 3) * 9216;
      float py = r0[0], pxf = r0[9216], m = r0[18432];
      float y0f = floorf(py), x0f = floorf(pxf);
      float ty = py - y0f, tx = pxf - x0f;
      int y0 = (int)y0f, x0 = (int)x0f;
      int y1 = y0 + 1, x1 = x0 + 1;
      float w00 = (1.f - ty) * (1.f - tx) * m, w01 = (1.f - ty) * tx * m;
      float w10 = ty * (1.f - tx) * m,         w11 = ty * tx * m;
      w00 = ((unsigned)y0 < HY && (unsigned)x0 < WY) ? w00 : 0.f;
      w01 = ((unsigned)y0 < HY && (unsigned)x1 < WY) ? w01 : 0.f;
      w10 = ((unsigned)y1 < HY && (unsigned)x0 < WY) ? w10 : 0.f;
      w11 = ((unsigned)y1 < HY && (unsigned)x1 < WY) ? w11 : 0.f;
      int y0c = min(max(y0, 0), HY - 1), y1c = min(max(y1, 0), HY - 1);
      int x0c = min(max(x0, 0), WY - 1), x1c = min(max(x1, 0), WY - 1);
      int gc = g * 8;
      const float* p00 = ytb + (size_t)(y0c * WY + x0c) * 64 + gc;
      const float* p01 = ytb + (size_t)(y0c * WY + x1c) * 64 + gc;
      const float* p10 = ytb + (size_t)(y1c * WY + x0c) * 64 + gc;
      const float* p11 = ytb + (size_t)(y1c * WY + x1c) * 64 + gc;
      float4 s0 = {0, 0, 0, 0}, s1 = {0, 0, 0, 0};
      float4 cA, cB;
      cA = *(const float4*)p00; cB = *(const float4*)(p00 + 4);
      MAD4(s0, cA, w00) MAD4(s1, cB, w00)
      cA = *(const float4*)p01; cB = *(const float4*)(p01 + 4);
      MAD4(s0, cA, w01) MAD4(s1, cB, w01)
      cA = *(const float4*)p10; cB = *(const float4*)(p10 + 4);
      MAD4(s0, cA, w10) MAD4(s1, cB, w10)
      cA = *(const float4*)p11; cB = *(const float4*)(p11 + 4);
      MAD4(s0, cA, w11) MAD4(s1, cB, w11)
      float* d = &sv[0][gc * 64 + gpx];
      d[0 * 64] = s0.x; d[1 * 64] = s0.y; d[2 * 64] = s0.z; d[3 * 64] = s0.w;
      d[4 * 64] = s1.x; d[5 * 64] = s1.y; d[6 * 64] = s1.z; d[7 * 64] = s1.w;
    }
  }
  __syncthreads();

#pragma unroll
  for (int i = 0; i < 2; ++i) {
    int k = k0 + i;
    // Phase A: rs prefetch for tap k+1
    float py[2], pxf[2], mq[2];
#pragma unroll
    for (int gg = 0; gg < 2; ++gg) {
      const float* r0 = rsb + (size_t)(((k + 1) * 8 + gb + gg * 4) * 3) * 9216;
      py[gg] = r0[0]; pxf[gg] = r0[9216]; mq[gg] = r0[18432];
    }
    DGEMM_HALF(k, i & 1, 0);
    // Phase B: addresses + issue 16 gather loads
    float4 L[2][4][2];
    float wts[2][4];
#pragma unroll
    for (int gg = 0; gg < 2; ++gg) {
      float y0f = floorf(py[gg]), x0f = floorf(pxf[gg]);
      float ty = py[gg] - y0f, tx = pxf[gg] - x0f;
      int y0 = (int)y0f, x0 = (int)x0f;
      int y1 = y0 + 1, x1 = x0 + 1;
      float m = mq[gg];
      float w00 = (1.f - ty) * (1.f - tx) * m, w01 = (1.f - ty) * tx * m;
      float w10 = ty * (1.f - tx) * m,         w11 = ty * tx * m;
      wts[gg][0] = ((unsigned)y0 < HY && (unsigned)x0 < WY) ? w00 : 0.f;
      wts[gg][1] = ((unsigned)y0 < HY && (unsigned)x1 < WY) ? w01 : 0.f;
      wts[gg][2] = ((unsigned)y1 < HY && (unsigned)x0 < WY) ? w10 : 0.f;
      wts[gg][3] = ((unsigned)y1 < HY && (unsigned)x1 < WY) ? w11 : 0.f;
      int y0c = min(max(y0, 0), HY - 1), y1c = min(max(y1, 0), HY - 1);
      int x0c = min(max(x0, 0), WY - 1), x1c = min(max(x1, 0), WY - 1);
      int gc = (gb + gg * 4) * 8;
      const float* p00 = ytb + (size_t)(y0c * WY + x0c) * 64 + gc;
      const float* p01 = ytb + (size_t)(y0c * WY + x1c) * 64 + gc;
      const float* p10 = ytb + (size_t)(y1c * WY + x0c) * 64 + gc;
      const float* p11 = ytb + (size_t)(y1c * WY + x1c) * 64 + gc;
      L[gg][0][0] = *(const float4*)p00; L[gg][0][1] = *(const float4*)(p00 + 4);
      L[gg][1][0] = *(const float4*)p01; L[gg][1][1] = *(const float4*)(p01 + 4);
      L[gg][2][0] = *(const float4*)p10; L[gg][2][1] = *(const float4*)(p10 + 4);
      L[gg][3][0] = *(const float4*)p11; L[gg][3][1] = *(const float4*)(p11 + 4);
    }
    DGEMM_HALF(k, i & 1, 32);
    // Phase C: combine + write next buffer
#pragma unroll
    for (int gg = 0; gg < 2; ++gg) {
      float4 s0 = {0, 0, 0, 0}, s1 = {0, 0, 0, 0};
      MAD4(s0, L[gg][0][0], wts[gg][0]) MAD4(s1, L[gg][0][1], wts[gg][0])
      MAD4(s0, L[gg][1][0], wts[gg][1]) MAD4(s1, L[gg][1][1], wts[gg][1])
      MAD4(s0, L[gg][2][0], wts[gg][2]) MAD4(s1, L[gg][2][1], wts[gg][2])
      MAD4(s0, L[gg][3][0], wts[gg][3]) MAD4(s1, L[gg][3][1], wts[gg][3])
      int gc = (gb + gg * 4) * 8;
      float* d = &sv[(i & 1) ^ 1][gc * 64 + gpx];
      d[0 * 64] = s0.x; d[1 * 64] = s0.y; d[2 * 64] = s0.z; d[3 * 64] = s0.w;
      d[4 * 64] = s1.x; d[5 * 64] = s1.y; d[6 * 64] = s1.z; d[7 * 64] = s1.w;
    }
    __syncthreads();
  }
  DGEMM_HALF(k0 + 2, 0, 0);
  DGEMM_HALF(k0 + 2, 0, 32);

  // store partials: pt[(p*576+tile)*4096 + oc*64 + px]
  float* pb = pt + (size_t)(p * 576 + tile576) * 4096;
#pragma unroll
  for (int i = 0; i < 4; ++i) {
    *(float4*)&pb[(4 * ocq + i) * 64 + 4 * pxq] =
        make_float4(acc[i][0], acc[i][1], acc[i][2], acc[i][3]);
  }
#undef DGEMM_HALF
}

// ---------- dreduce: sum 3 deform parts + bias + relu -> out ----------
__global__ __launch_bounds__(256) void dreduce_kernel(
    const float* __restrict__ pt, const float* __restrict__ bdc,
    float* __restrict__ out) {
  int tile = blockIdx.x;  // 0..575
  int b = tile / 144;
  int tl = tile % 144;
  int h0 = (tl / 12) * 8;
  int w0 = (tl % 12) * 8;
  int n = threadIdx.x;
  int oc = n >> 2;
  const float4* p0 = (const float4*)(pt + (size_t)(0 * 576 + tile) * 4096);
  const float4* p1 = (const float4*)(pt + (size_t)(1 * 576 + tile) * 4096);
  const float4* p2 = (const float4*)(pt + (size_t)(2 * 576 + tile) * 4096);
  float bv = bdc[oc];
#pragma unroll
  for (int q = 0; q < 4; ++q) {
    int j = n * 4 + q;          // f4 idx: oc*16 + pq
    int pq = j & 15;
    int py = pq >> 1;
    int colb = (pq & 1) * 4;
    float4 a = p0[j], c = p1[j], d = p2[j];
    float4 o;
    o.x = fmaxf(a.x + c.x + d.x + bv, 0.f);
    o.y = fmaxf(a.y + c.y + d.y + bv, 0.f);
    o.z = fmaxf(a.z + c.z + d.z + bv, 0.f);
    o.w = fmaxf(a.w + c.w + d.w + bv, 0.f);
    *(float4*)&out[((size_t)(b * 64 + oc) * 96 + (h0 + py)) * 96 + w0 + colb] = o;
  }
}

extern "C" void kernel_launch(void* const* d_in, const int* in_sizes, int n_in,
                              void* d_out, int out_size, void* d_ws, size_t ws_size,
                              hipStream_t stream) {
  const float* x = (const float*)d_in[0];
  const float* y = (const float*)d_in[1];
  const float* w_om = (const float*)d_in[2];
  const float* b_om = (const float*)d_in[3];
  const float* w_dc = (const float*)d_in[4];
  const float* b_dc = (const float*)d_in[5];
  float* out = (float*)d_out;

  float* om  = (float*)d_ws;           // 1,990,656 f
  float* wt2 = om + 1990656;           //   147,456 f
  float* wt1 = wt2 + 147456;           //    36,864 f
  float* yt  = wt1 + 36864;            // 2,359,296 f
  float* shr = yt + 2359296;           // 7,962,624 f (pc then rs)
  float* pc  = shr;                    // 7,077,888 f (dead before rs written)
  float* rs  = shr;                    // 7,962,624 f
  float* pt  = shr + 7962624;          // 7,077,888 f

  prep_w_kernel<<<720, 256, 0, stream>>>(w_om, w_dc, wt2, wt1);
  ytr_kernel<<<576, 256, 0, stream>>>(y, yt);
  conv_part_kernel<<<1728, 256, 0, stream>>>(x, wt2, pc);
  creduce_kernel<<<576, 256, 0, stream>>>(pc, b_om, om);
  resize_kernel<<<10368, 256, 0, stream>>>(om, rs);
  deform_part_kernel<<<1728, 256, 0, stream>>>(yt, rs, wt1, pt);
  dreduce_kernel<<<576, 256, 0, stream>>>(pt, b_dc, out);
}